// Round 9
// baseline (515.309 us; speedup 1.0000x reference)
//
#include <hip/hip_runtime.h>
#include <hip/hip_fp16.h>
#include <stdint.h>

// Problem constants: B=4, S=128 -> M=512
#define M_DIM 512
#define K_DIM 4096
#define N_DIM 11008
#define KT (K_DIM / 64)        // 64 k-tiles of BK=64
#define NBLK (8 * 172)         // 1376 two-wave blocks (wave = 64m x 32n x full K)

typedef __attribute__((ext_vector_type(8))) _Float16 half8;
typedef __attribute__((ext_vector_type(4))) float floatx4;
typedef __attribute__((ext_vector_type(4))) unsigned int uintx4;

__device__ __forceinline__ unsigned int h2u(__half2 h) {
    union { __half2 h; unsigned int u; } c; c.h = h; return c.u;
}
__device__ __forceinline__ __half2 u2h(unsigned int u) {
    union { unsigned int u; __half2 h; } c; c.u = u; return c.h;
}
union U4H8 { uintx4 u; half8 h; };

// RAW-code dequant: 8 int32 codes (values 0..15) -> half8. Cheaper than the
// old nibble path: d|d'<<16|bias needs no masking since codes < 16.
__device__ __forceinline__ half8 dq8(uintx4 a, uintx4 b, __half2 s2, __half2 z2) {
    const __half2 kb = u2h(0x64006400u);   // (1024, 1024)
    U4H8 r;
    r.u.x = h2u(__hfma2(__hsub2(u2h((a.x | (a.y << 16)) | 0x64006400u), kb), s2, z2));
    r.u.y = h2u(__hfma2(__hsub2(u2h((a.z | (a.w << 16)) | 0x64006400u), kb), s2, z2));
    r.u.z = h2u(__hfma2(__hsub2(u2h((b.x | (b.y << 16)) | 0x64006400u), kb), s2, z2));
    r.u.w = h2u(__hfma2(__hsub2(u2h((b.z | (b.w << 16)) | 0x64006400u), kb), s2, z2));
    return r.h;
}

// ---------------------------------------------------------------------------
// cvt: x fp32 [512,4096] -> f16 fragment-linear xb (R5-proven map, unchanged).
// The 180 MB pack kernel is GONE — gemm reads wq directly (fusion removes a
// full extra pass over the weight stream: was 180 read + 22.5 write + ~107
// cold re-fetch across two kernels).
// ---------------------------------------------------------------------------
__global__ __launch_bounds__(256) void cvt_kernel(
        const float* __restrict__ x, unsigned int* __restrict__ xb) {
    int id = blockIdx.x * 256 + threadIdx.x;   // chunk id, 262144 total
    int m  = id >> 9;
    int kc = id & 511;                          // k-octet within row
    const floatx4* src = (const floatx4*)(x + ((size_t)m << 12) + (kc << 3));
    floatx4 f0 = src[0];
    floatx4 f1 = src[1];
    uintx4 v;
    v.x = h2u(__float22half2_rn(float2{f0.x, f0.y}));
    v.y = h2u(__float22half2_rn(float2{f0.z, f0.w}));
    v.z = h2u(__float22half2_rn(float2{f1.x, f1.y}));
    v.w = h2u(__float22half2_rn(float2{f1.z, f1.w}));
    int tm = m >> 7, r = m & 127, tk = kc >> 3, c = kc & 7;
    int igrp = r >> 4, rlow = r & 15, s01 = c >> 2, q = c & 3;
    int chunk = ((igrp * 2 + s01) << 6) + (q << 4) + rlow;
    size_t dstu = (((size_t)(tm * KT + tk)) << 12) + ((size_t)chunk << 2);
    *((uintx4*)(xb + dstu)) = v;
}

// ---------------------------------------------------------------------------
// FUSED GEMM: reads RAW wq once (the only pass over the 180 MB stream).
// 2 waves/block, wave-private: wave wid owns 64 m-rows x 32 n-cols x full K.
// Per k-tile the wave stages its 32 rows x 256 B of wq into its own 8 KB LDS
// buffer: 8x 16 B/lane nontemporal loads, 4 rows x 2 FULL 128 B lines per
// instruction (coalesced), source pre-swizzled byte ^= (row&7)<<5 + linear
// LDS write, so frag ds_reads are conflict-light. Same-wave DS ops are
// in-order -> NO barriers, no cross-wave deps. Stage regs double-buffered
// (sA/sB, static via unroll-2); compiler's counted vmcnt covers the HBM
// latency with the full MFMA+dequant body. Epilogue: direct stores (each
// wave owns distinct output columns) — no LDS reduction, no atomics.
// ---------------------------------------------------------------------------
__global__ __launch_bounds__(128, 2) void gemm_kernel(
        const unsigned int* __restrict__ xb,    // fragment-linear f16 x
        const int*          __restrict__ wq,    // RAW codes [N][K] int32 0..15
        const float*        __restrict__ saz,   // [K/128, N, 2]
        float*              __restrict__ out)   // [M,N] fp32 (fully written here)
{
    const int bx   = blockIdx.x;
    const int mbp  = bx & 7;                   // 64-row strip (== XCD id)
    const int nbp  = bx >> 3;                  // 64-col strip 0..171
    const int lane = threadIdx.x & 63;
    const int wid  = threadIdx.x >> 6;         // n-half 0/1
    const int q4   = lane >> 4;
    const int lr   = lane & 15;

    const int tm    = mbp >> 1;                // xb 128-row tile
    const int igrp0 = (mbp & 1) * 4;           // first 16-row group
    const int n0w   = nbp * 64 + wid * 32;     // wave's first n-row

    __shared__ uintx4 ldsq[1024];              // 16 KB = 2 waves x 8 KB
    char* wbuf = (char*)(ldsq + (wid << 9));

    // stage addressing: round u (0..7), lane: row = u*4 + (lane>>4),
    // src col byte = ((lane&15)*16) ^ ((row&7)<<5); LDS dst = linear lane*16.
    const int cb   = (lane & 15) << 4;
    const int col0 = cb ^ (q4 << 5);           // row&7 = (u&1)*4 + q4
    const int col1 = col0 ^ 128;
    const char* wrow = (const char*)wq + ((size_t)(n0w + q4) << 14);  // row stride 16 KB

    // ds_read byte offsets per (s01, j): row = j*16+lr, col = (s01*4+q4)*32
    int roff[2][2];
#pragma unroll
    for (int s01 = 0; s01 < 2; ++s01)
#pragma unroll
        for (int j = 0; j < 2; ++j)
            roff[s01][j] = (j * 16 + lr) * 256
                         + (((s01 * 4 + q4) * 32) ^ ((lr & 7) << 5));

    // A fragments (shared n-independent): same per-lane layout as before
    const half8* xat = (const half8*)xb
        + (((size_t)(tm * KT)) << 10) + (igrp0 << 7) + lane;

    // scales: wave's 2 n-frags
    const float2* sazp = (const float2*)saz + (n0w + lr);
    float2 sf0 = sazp[0], sf1 = sazp[16];
    __half2 s2_0, z2_0, s2_1, z2_1;

    floatx4 acc[4][2];
    floatx4 zero4 = {0.f, 0.f, 0.f, 0.f};
#pragma unroll
    for (int i = 0; i < 4; ++i)
#pragma unroll
        for (int j = 0; j < 2; ++j)
            acc[i][j] = zero4;

    // prologue: stage tile kt=0 into sA
    uintx4 sA[8], sB[8];
#pragma unroll
    for (int u = 0; u < 8; ++u)
        sA[u] = __builtin_nontemporal_load(
            (const uintx4*)(wrow + u * 65536 + ((u & 1) ? col1 : col0)));

// one k-tile: stage next into SN, ds_write SC (auto-waits its vmcnt),
// ds_read frags, dequant+MFMA. EVEN: scale-convert; odd: scale-prefetch.
#define GB(SC, SN, EVEN, MORE)                                                \
    {                                                                         \
        if (MORE) {                                                           \
            const char* w2 = wrow + 256;                                      \
            _Pragma("unroll")                                                 \
            for (int u = 0; u < 8; ++u)                                       \
                SN[u] = __builtin_nontemporal_load(                           \
                    (const uintx4*)(w2 + u * 65536 + ((u & 1) ? col1 : col0)));\
        }                                                                     \
        half8 av[8];                                                          \
        _Pragma("unroll")                                                     \
        for (int i = 0; i < 4; ++i) {                                         \
            av[i * 2]     = xat[i * 128];                                     \
            av[i * 2 + 1] = xat[i * 128 + 64];                                \
        }                                                                     \
        if (EVEN) {                                                           \
            s2_0 = __float2half2_rn(sf0.x);                                   \
            z2_0 = __float2half2_rn(fmaf(-8.f, sf0.x, sf0.y));                \
            s2_1 = __float2half2_rn(sf1.x);                                   \
            z2_1 = __float2half2_rn(fmaf(-8.f, sf1.x, sf1.y));                \
        } else if (MORE) {                                                    \
            sazp += N_DIM;                                                    \
            sf0 = sazp[0];                                                    \
            sf1 = sazp[16];                                                   \
        }                                                                     \
        _Pragma("unroll")                                                     \
        for (int u = 0; u < 8; ++u)                                           \
            *(uintx4*)(wbuf + u * 1024 + (lane << 4)) = SC[u];                \
        _Pragma("unroll")                                                     \
        for (int s01 = 0; s01 < 2; ++s01) {                                   \
            _Pragma("unroll")                                                 \
            for (int j = 0; j < 2; ++j) {                                     \
                uintx4 d0 = *(const uintx4*)(wbuf + roff[s01][j]);            \
                uintx4 d1 = *(const uintx4*)(wbuf + roff[s01][j] + 16);       \
                half8 bv = dq8(d0, d1, (j ? s2_1 : s2_0), (j ? z2_1 : z2_0)); \
                _Pragma("unroll")                                             \
                for (int i = 0; i < 4; ++i)                                   \
                    acc[i][j] = __builtin_amdgcn_mfma_f32_16x16x32_f16(       \
                        av[i * 2 + s01], bv, acc[i][j], 0, 0, 0);             \
            }                                                                 \
        }                                                                     \
        xat  += 1024;                                                         \
        wrow += 256;                                                          \
    }

    for (int kp = 0; kp < 32; ++kp) {          // kt pair (2kp, 2kp+1)
        GB(sA, sB, 1, true)
        GB(sB, sA, 0, (kp < 31))
    }
#undef GB

    // Epilogue: C/D layout col = lane&15 (n), row = q4*4 + reg (m).
    // Wave owns its columns exclusively — direct stores.
    const int n0 = n0w + lr;
#pragma unroll
    for (int i = 0; i < 4; ++i)
#pragma unroll
        for (int j = 0; j < 2; ++j) {
            float* o = out + (size_t)(mbp * 64 + i * 16 + q4 * 4) * N_DIM
                     + (n0 + j * 16);
#pragma unroll
            for (int rr = 0; rr < 4; ++rr)
                o[(size_t)rr * N_DIM] = acc[i][j][rr];
        }
}

extern "C" void kernel_launch(void* const* d_in, const int* in_sizes, int n_in,
                              void* d_out, int out_size, void* d_ws, size_t ws_size,
                              hipStream_t stream) {
    const float* x   = (const float*)d_in[0];
    const int*   wq  = (const int*)d_in[1];
    const float* saz = (const float*)d_in[2];

    // ws layout: [xb: 4 MB f16 x]  (wpk intermediate is gone)
    unsigned int* xb = (unsigned int*)d_ws;

    cvt_kernel<<<dim3(1024), dim3(256), 0, stream>>>(x, xb);
    gemm_kernel<<<dim3(NBLK), dim3(128), 0, stream>>>(xb, wq, saz, (float*)d_out);
}

// Round 10
// 360.005 us; speedup vs baseline: 1.4314x; 1.4314x over previous
//
#include <hip/hip_runtime.h>
#include <hip/hip_fp16.h>
#include <stdint.h>

// Problem constants: B=4, S=128 -> M=512
#define M_DIM 512
#define K_DIM 4096
#define N_DIM 11008
#define KT (K_DIM / 64)        // 64 k-tiles of BK=64
#define NB_M 8                 // 64-row strips
#define NB_N 172               // 64-col strips
#define NBLK (NB_M * NB_N)     // 1376 two-wave blocks (split-K=2 inside the block)

typedef __attribute__((ext_vector_type(8))) _Float16 half8;
typedef __attribute__((ext_vector_type(4))) float floatx4;
typedef __attribute__((ext_vector_type(4))) int intx4;
typedef __attribute__((ext_vector_type(4))) unsigned int uintx4;

__device__ __forceinline__ unsigned int h2u(__half2 h) {
    union { __half2 h; unsigned int u; } c; c.h = h; return c.u;
}
__device__ __forceinline__ __half2 u2h(unsigned int u) {
    union { unsigned int u; __half2 h; } c; c.u = u; return c.h;
}
union U4H8 { uintx4 u; half8 h; };

// one packed dword (8 codes, pair-interleaved) -> b-operand half8 (R5-proven)
__device__ __forceinline__ half8 dequant8(unsigned int dw, __half2 s2, __half2 z2) {
    const __half2 kb = u2h(0x64006400u);   // (1024, 1024)
    U4H8 r;
    unsigned int p0 = (dw & 0x000F000Fu) | 0x64006400u;
    unsigned int p1 = ((dw >> 4)  & 0x000F000Fu) | 0x64006400u;
    unsigned int p2 = ((dw >> 8)  & 0x000F000Fu) | 0x64006400u;
    unsigned int p3 = ((dw >> 12) & 0x000F000Fu) | 0x64006400u;
    r.u.x = h2u(__hfma2(__hsub2(u2h(p0), kb), s2, z2));
    r.u.y = h2u(__hfma2(__hsub2(u2h(p1), kb), s2, z2));
    r.u.z = h2u(__hfma2(__hsub2(u2h(p2), kb), s2, z2));
    r.u.w = h2u(__hfma2(__hsub2(u2h(p3), kb), s2, z2));
    return r.h;
}

// ---------------------------------------------------------------------------
// Merged prep kernel — EXACT R8 version (proven). Load side = R2 pattern
// (4 lanes/line on the 180 MB wq stream); wpk tile layout LANE-LINEAR:
//   idx' = h*512 + (q4*16 + lr)*8 + s01*4 + j
// so each gemm lane's 8 dwords/kt are contiguous 32 B (2x dwordx4 per wave).
// ---------------------------------------------------------------------------
__global__ __launch_bounds__(256) void prep_kernel(
        const float* __restrict__ x,  unsigned int* __restrict__ xb,
        const int*   __restrict__ wq, unsigned int* __restrict__ wpk) {
    int bx = blockIdx.x;
    if (bx < 1024) {
        int id = bx * 256 + threadIdx.x;        // chunk id, 262144 total
        int m  = id >> 9;
        int kc = id & 511;                      // k-octet within row
        const floatx4* src = (const floatx4*)(x + ((size_t)m << 12) + (kc << 3));
        floatx4 f0 = __builtin_nontemporal_load(src);
        floatx4 f1 = __builtin_nontemporal_load(src + 1);
        uintx4 v;
        v.x = h2u(__float22half2_rn(float2{f0.x, f0.y}));
        v.y = h2u(__float22half2_rn(float2{f0.z, f0.w}));
        v.z = h2u(__float22half2_rn(float2{f1.x, f1.y}));
        v.w = h2u(__float22half2_rn(float2{f1.z, f1.w}));
        int tm = m >> 7, r = m & 127, tk = kc >> 3, c = kc & 7;
        int igrp = r >> 4, rlow = r & 15, s01 = c >> 2, q = c & 3;
        int chunk = ((igrp * 2 + s01) << 6) + (q << 4) + rlow;
        size_t dstu = (((size_t)(tm * KT + tk)) << 12) + ((size_t)chunk << 2);
        *((uintx4*)(xb + dstu)) = v;
    } else {
        int id   = (bx - 1024) * 256 + threadIdx.x;
        int tile = id >> 9;                     // 5504 tiles (86 nb x 64 kt)
        int p    = id & 511;
        int nb = tile >> 6, kt = tile & 63;
        int r = p >> 2, q0 = (p & 3) * 2;       // r = n-row, q0 = even k-octet
        const intx4* src = (const intx4*)(wq + (size_t)(nb * 128 + r) * K_DIM + kt * 64 + q0 * 8);
        intx4 a0 = __builtin_nontemporal_load(src);
        intx4 a1 = __builtin_nontemporal_load(src + 1);
        intx4 a2 = __builtin_nontemporal_load(src + 2);
        intx4 a3 = __builtin_nontemporal_load(src + 3);
        unsigned int u0 =
            (unsigned)a0.x | ((unsigned)a0.z << 4)  | ((unsigned)a1.x << 8)  | ((unsigned)a1.z << 12) |
            ((unsigned)a0.y << 16) | ((unsigned)a0.w << 20) | ((unsigned)a1.y << 24) | ((unsigned)a1.w << 28);
        unsigned int u1 =
            (unsigned)a2.x | ((unsigned)a2.z << 4)  | ((unsigned)a3.x << 8)  | ((unsigned)a3.z << 12) |
            ((unsigned)a2.y << 16) | ((unsigned)a2.w << 20) | ((unsigned)a3.y << 24) | ((unsigned)a3.w << 28);
        int hh = r >> 6, lr2 = r & 15, j2 = (r & 63) >> 4;
        size_t i0 = (((size_t)tile) << 10) + (hh << 9)
                  + (((q0 & 3) << 4) + lr2) * 8 + ((q0 >> 2) << 2) + j2;
        wpk[i0]       = u0;                     // q = q0
        wpk[i0 + 128] = u1;                     // q = q0+1
    }
}

// ---------------------------------------------------------------------------
// GEMM. Two waves per block, split-K=2 in-block (proven R4/R8 structure).
// DELTA vs R8 (one register-budget transaction):
//   * 4-SLOT W buffering in a 4-kt unrolled group: slot k (w{k}a/w{k}b) is
//     reloaded immediately after its dequant consumes it; next use is 4 kt
//     later -> prefetch lead ~1400 cyc >> the ~600 cyc L2-miss->L3 latency
//     of the W stream (which CANNOT be L2-resident: each XCD's 172 blocks
//     stream all 22.5 MB of wpk through 4 MB L2; mbp-pinning is needed to
//     keep A L2-resident). Zero rotation movs — all indices static.
//   * av split-pipelining dropped to pay for the 2 extra W slots: A is an
//     L2-hit stream (~200 cyc), the cheapest latency to expose. Net VGPR
//     ~= R8's 136 (R7's depth-2 attempt ADDED 8 on top of the split ->
//     148 total, likely crossing an occupancy quantum -> its regression).
// Scale schedule = R4-proven (convert on even kt, prefetch on odd kt).
// Epilogue = R8 (LDS pairwise reduction, plain stores, no atomics).
// ---------------------------------------------------------------------------
__global__ __launch_bounds__(128, 3) void gemm_kernel(
        const unsigned int* __restrict__ xb,    // fragment-linear f16 x
        const unsigned int* __restrict__ wpk,   // packed nibbles, lane-linear tiles
        const float*        __restrict__ saz,   // [K/128, N, 2]
        float*              __restrict__ out)   // [M,N] fp32 (fully written here)
{
    const int bx   = blockIdx.x;
    const int mbp  = bx & 7;                   // 64-row strip 0..7 (== XCD id)
    const int nbp  = bx >> 3;                  // 64-col strip 0..171
    const int lane = threadIdx.x & 63;
    const int wid  = threadIdx.x >> 6;         // split-K half 0/1
    const int q4   = lane >> 4;
    const int lr   = lane & 15;
    const int kt0  = wid * (KT / 2);

    const int tm    = mbp >> 1;                // xb 128-row tile
    const int igrp0 = (mbp & 1) * 4;           // first 16-row group
    const int nbt   = nbp >> 1;                // wpk 128-col tile
    const int hh    = nbp & 1;                 // n-half within the 128-col tile

    // A fragments: 16 B units; frag (i, s01) at xat[i*128 + s01*64]
    const half8* xat = (const half8*)xb
        + (((size_t)(tm * KT + kt0)) << 10) + (igrp0 << 7) + lane;

    // W: lane-linear — this lane's 8 dwords/kt at 2x uintx4; 256 uintx4/kt
    const uintx4* wb4 = (const uintx4*)
        (wpk + (((size_t)(nbt * KT + kt0)) << 10) + (hh << 9)) + lane * 2;

    const float2* saz2 = (const float2*)saz;
    const int nrow0 = nbp * 64 + lr;           // n-row for frag j: +j*16
    const float2* sazp = saz2 + (size_t)(kt0 >> 1) * N_DIM + nrow0;

    floatx4 acc[4][4];
    floatx4 zero4 = {0.f, 0.f, 0.f, 0.f};
#pragma unroll
    for (int i = 0; i < 4; ++i)
#pragma unroll
        for (int j = 0; j < 4; ++j)
            acc[i][j] = zero4;

    // prologue: fill all 4 W slots (kt0 .. kt0+3), scales for group 0
    uintx4 w0a, w0b, w1a, w1b, w2a, w2b, w3a, w3b;
    w0a = wb4[0];    w0b = wb4[1];
    w1a = wb4[256];  w1b = wb4[257];
    w2a = wb4[512];  w2b = wb4[513];
    w3a = wb4[768];  w3b = wb4[769];
    wb4 += 1024;                               // -> kt0+4 (prefetch base)

    float2 sf[4];
#pragma unroll
    for (int t = 0; t < 4; ++t)
        sf[t] = sazp[t * 16];

    __half2 s2[4], z2[4];

// one k-tile: SOP 0 = convert scales, 1 = prefetch scales (guarded by PF for
// the last group). WA/WB = this kt's W slot halves; prefetch reload after use.
#define KTBODY(WA, WB, SOP, PF, POFF)                                         \
    {                                                                         \
        if (SOP == 0) {                                                       \
            _Pragma("unroll")                                                 \
            for (int t = 0; t < 4; ++t) {                                     \
                s2[t] = __float2half2_rn(sf[t].x);                            \
                z2[t] = __float2half2_rn(fmaf(-8.f, sf[t].x, sf[t].y));       \
            }                                                                 \
        } else if (PF) {                                                      \
            sazp += N_DIM;                                                    \
            _Pragma("unroll")                                                 \
            for (int t = 0; t < 4; ++t)                                       \
                sf[t] = sazp[t * 16];                                         \
        }                                                                     \
        half8 av[8];                                                          \
        _Pragma("unroll")                                                     \
        for (int i = 0; i < 4; ++i) {                                         \
            av[i * 2]     = xat[i * 128];                                     \
            av[i * 2 + 1] = xat[i * 128 + 64];                                \
        }                                                                     \
        _Pragma("unroll")                                                     \
        for (int j = 0; j < 4; ++j) {                                         \
            half8 bv = dequant8(WA[j], s2[j], z2[j]);                         \
            _Pragma("unroll")                                                 \
            for (int i = 0; i < 4; ++i)                                       \
                acc[i][j] = __builtin_amdgcn_mfma_f32_16x16x32_f16(           \
                    av[i * 2], bv, acc[i][j], 0, 0, 0);                       \
        }                                                                     \
        _Pragma("unroll")                                                     \
        for (int j = 0; j < 4; ++j) {                                         \
            half8 bv = dequant8(WB[j], s2[j], z2[j]);                         \
            _Pragma("unroll")                                                 \
            for (int i = 0; i < 4; ++i)                                       \
                acc[i][j] = __builtin_amdgcn_mfma_f32_16x16x32_f16(           \
                    av[i * 2 + 1], bv, acc[i][j], 0, 0, 0);                   \
        }                                                                     \
        if (PF) {                                                             \
            WA = wb4[POFF];                                                   \
            WB = wb4[POFF + 1];                                               \
        }                                                                     \
        xat += 1024;                                                          \
    }

    for (int g = 0; g < 8; ++g) {              // 8 groups x 4 kt = 32 kt
        const bool pf = (g < 7);
        KTBODY(w0a, w0b, 0, pf, 0)             // even kt: convert scales
        KTBODY(w1a, w1b, 1, true, 256)         // odd kt: prefetch scales
        KTBODY(w2a, w2b, 0, pf, 512)
        KTBODY(w3a, w3b, 1, pf, 768)
        wb4 += 1024;
    }
#undef KTBODY

    // ---------------------------------------------------------------------
    // Epilogue: C/D layout col = lane&15 (n), row = q4*4 + reg (m).
    // Cross-wave reduction through padded LDS; plain stores, no atomics.
    // ---------------------------------------------------------------------
    __shared__ float red[2][32 * 65];
    float* don = red[wid];
    const int id0 = wid ? 0 : 2;               // donated i-range
#pragma unroll
    for (int ii = 0; ii < 2; ++ii) {
        const int i = id0 + ii;
#pragma unroll
        for (int j = 0; j < 4; ++j)
#pragma unroll
            for (int rr = 0; rr < 4; ++rr) {
                const int rl = (i * 16 + q4 * 4 + rr) & 31;
                don[rl * 65 + j * 16 + lr] = acc[i][j][rr];
            }
    }
    __syncthreads();
    const float* oth = red[wid ^ 1];
    const int ik0 = wid ? 2 : 0;               // kept i-range
    const int n0 = nbp * 64 + lr;
#pragma unroll
    for (int ii = 0; ii < 2; ++ii) {
        const int i = ik0 + ii;
#pragma unroll
        for (int j = 0; j < 4; ++j) {
            float* o = out + (size_t)(mbp * 64 + i * 16 + q4 * 4) * N_DIM + (n0 + j * 16);
#pragma unroll
            for (int rr = 0; rr < 4; ++rr) {
                const int rl = (i * 16 + q4 * 4 + rr) & 31;
                o[(size_t)rr * N_DIM] = acc[i][j][rr] + oth[rl * 65 + j * 16 + lr];
            }
        }
    }
}

extern "C" void kernel_launch(void* const* d_in, const int* in_sizes, int n_in,
                              void* d_out, int out_size, void* d_ws, size_t ws_size,
                              hipStream_t stream) {
    const float* x   = (const float*)d_in[0];
    const int*   wq  = (const int*)d_in[1];
    const float* saz = (const float*)d_in[2];

    // ws layout: [wpk: 22,544,384 B packed weights][xb: 4 MB f16 x]
    unsigned int* wpk = (unsigned int*)d_ws;
    unsigned int* xb  = (unsigned int*)((char*)d_ws + 22544384);

    // No output memset: gemm writes every element exactly once (no atomics).
    prep_kernel<<<dim3(12032), dim3(256), 0, stream>>>(x, xb, wq, wpk);
    gemm_kernel<<<dim3(NBLK), dim3(128), 0, stream>>>(xb, wpk, saz, (float*)d_out);
}

// Round 11
// 355.842 us; speedup vs baseline: 1.4481x; 1.0117x over previous
//
#include <hip/hip_runtime.h>
#include <hip/hip_fp16.h>
#include <stdint.h>

// Problem constants: B=4, S=128 -> M=512
#define M_DIM 512
#define K_DIM 4096
#define N_DIM 11008
#define KT (K_DIM / 64)        // 64 k-tiles of BK=64
#define NB_M 8                 // 64-row strips
#define NB_N 172               // 64-col strips
#define NBLK (NB_M * NB_N)     // 1376 two-wave blocks (split-K=2 inside the block)

typedef __attribute__((ext_vector_type(8))) _Float16 half8;
typedef __attribute__((ext_vector_type(4))) float floatx4;
typedef __attribute__((ext_vector_type(4))) int intx4;
typedef __attribute__((ext_vector_type(4))) unsigned int uintx4;

__device__ __forceinline__ unsigned int h2u(__half2 h) {
    union { __half2 h; unsigned int u; } c; c.h = h; return c.u;
}
__device__ __forceinline__ __half2 u2h(unsigned int u) {
    union { unsigned int u; __half2 h; } c; c.u = u; return c.h;
}
union U4H8 { uintx4 u; half8 h; };

// one packed dword (8 codes, pair-interleaved) -> b-operand half8 (R5-proven)
__device__ __forceinline__ half8 dequant8(unsigned int dw, __half2 s2, __half2 z2) {
    const __half2 kb = u2h(0x64006400u);   // (1024, 1024)
    U4H8 r;
    unsigned int p0 = (dw & 0x000F000Fu) | 0x64006400u;
    unsigned int p1 = ((dw >> 4)  & 0x000F000Fu) | 0x64006400u;
    unsigned int p2 = ((dw >> 8)  & 0x000F000Fu) | 0x64006400u;
    unsigned int p3 = ((dw >> 12) & 0x000F000Fu) | 0x64006400u;
    r.u.x = h2u(__hfma2(__hsub2(u2h(p0), kb), s2, z2));
    r.u.y = h2u(__hfma2(__hsub2(u2h(p1), kb), s2, z2));
    r.u.z = h2u(__hfma2(__hsub2(u2h(p2), kb), s2, z2));
    r.u.w = h2u(__hfma2(__hsub2(u2h(p3), kb), s2, z2));
    return r.h;
}

// ---------------------------------------------------------------------------
// Merged prep kernel — EXACT R2/R4 version (proven; R3's "coalesced" pack
// remap regressed 31 us by scattering per-instruction wq loads across 64
// cache lines on the 180 MB stream).
// Blocks [0,1024): x fp32 -> f16 fragment-linear xb. Blocks [1024,12032):
// wq int32 -> packed nibbles, tile-major [nb][kt], dword idx = q*128 + r.
// ---------------------------------------------------------------------------
__global__ __launch_bounds__(256) void prep_kernel(
        const float* __restrict__ x,  unsigned int* __restrict__ xb,
        const int*   __restrict__ wq, unsigned int* __restrict__ wpk) {
    int bx = blockIdx.x;
    if (bx < 1024) {
        int id = bx * 256 + threadIdx.x;        // chunk id, 262144 total
        int m  = id >> 9;
        int kc = id & 511;                      // k-octet within row
        const floatx4* src = (const floatx4*)(x + ((size_t)m << 12) + (kc << 3));
        floatx4 f0 = __builtin_nontemporal_load(src);
        floatx4 f1 = __builtin_nontemporal_load(src + 1);
        uintx4 v;
        v.x = h2u(__float22half2_rn(float2{f0.x, f0.y}));
        v.y = h2u(__float22half2_rn(float2{f0.z, f0.w}));
        v.z = h2u(__float22half2_rn(float2{f1.x, f1.y}));
        v.w = h2u(__float22half2_rn(float2{f1.z, f1.w}));
        int tm = m >> 7, r = m & 127, tk = kc >> 3, c = kc & 7;
        int igrp = r >> 4, rlow = r & 15, s01 = c >> 2, q = c & 3;
        int chunk = ((igrp * 2 + s01) << 6) + (q << 4) + rlow;
        size_t dstu = (((size_t)(tm * KT + tk)) << 12) + ((size_t)chunk << 2);
        *((uintx4*)(xb + dstu)) = v;
    } else {
        int id   = (bx - 1024) * 256 + threadIdx.x;
        int tile = id >> 9;                     // 5504 tiles (86 nb x 64 kt)
        int p    = id & 511;
        int nb = tile >> 6, kt = tile & 63;
        int r = p >> 2, q0 = (p & 3) * 2;
        const intx4* src = (const intx4*)(wq + (size_t)(nb * 128 + r) * K_DIM + kt * 64 + q0 * 8);
        intx4 a0 = __builtin_nontemporal_load(src);
        intx4 a1 = __builtin_nontemporal_load(src + 1);
        intx4 a2 = __builtin_nontemporal_load(src + 2);
        intx4 a3 = __builtin_nontemporal_load(src + 3);
        unsigned int u0 =
            (unsigned)a0.x | ((unsigned)a0.z << 4)  | ((unsigned)a1.x << 8)  | ((unsigned)a1.z << 12) |
            ((unsigned)a0.y << 16) | ((unsigned)a0.w << 20) | ((unsigned)a1.y << 24) | ((unsigned)a1.w << 28);
        unsigned int u1 =
            (unsigned)a2.x | ((unsigned)a2.z << 4)  | ((unsigned)a3.x << 8)  | ((unsigned)a3.z << 12) |
            ((unsigned)a2.y << 16) | ((unsigned)a2.w << 20) | ((unsigned)a3.y << 24) | ((unsigned)a3.w << 28);
        size_t base = ((size_t)tile) << 10;
        wpk[base + (q0 << 7) + r]       = u0;
        wpk[base + ((q0 + 1) << 7) + r] = u1;
    }
}

// ---------------------------------------------------------------------------
// GEMM. Two waves per block, split-K=2 inside the block (R2 structure).
// FULLY SOFTWARE-PIPELINED LOADS (R4 — measured best, 354.2 us):
//   * A split into s0/s1 halves: s1 loads issue before the s0 MFMA block
//     (~310 cyc of cover), next-kt s0 loads issue between the MFMA blocks.
//   * scales prefetched one kt ahead as raw float2 (converted VALU-only at
//     the consuming even kt).
//   * W prefetched one k-tile ahead (qw/qwn rotation, depth-1 — depths 2
//     and 4 both measured slower in R7/R10).
// ---------------------------------------------------------------------------
__global__ __launch_bounds__(128, 3) void gemm_kernel(
        const unsigned int* __restrict__ xb,    // fragment-linear f16 x
        const unsigned int* __restrict__ wpk,   // packed nibbles, [q][r] tiles
        const float*        __restrict__ saz,   // [K/128, N, 2]
        float*              __restrict__ out)   // [M,N] fp32 (fully written here)
{
    const int bx   = blockIdx.x;
    const int mbp  = bx & 7;                   // 64-row strip 0..7
    const int nbp  = bx >> 3;                  // 64-col strip 0..171
    const int lane = threadIdx.x & 63;
    const int wid  = threadIdx.x >> 6;         // split-K half 0/1
    const int q4   = lane >> 4;
    const int lr   = lane & 15;
    const int kt0  = wid * (KT / 2);
    const int kt1  = kt0 + (KT / 2);           // 32 k-tiles per wave

    const int tm    = mbp >> 1;                // xb 128-row tile
    const int igrp0 = (mbp & 1) * 4;           // first 16-row group
    const int nbt   = nbp >> 1;                // wpk 128-col tile
    const int wn    = (nbp & 1) * 64;

    // A fragments: 16 B units; frag (i, s01) at xat[i*128 + s01*64]
    const half8* xat = (const half8*)xb
        + (((size_t)(tm * KT + kt0)) << 10) + (igrp0 << 7) + lane;

    // W: frag (j, s01) at wbase[s01*512 + j*16]; advance 1024 dwords/k-tile
    const unsigned int* wbase =
        wpk + (((size_t)(nbt * KT + kt0)) << 10) + (q4 << 7) + wn + lr;

    const float2* saz2 = (const float2*)saz;
    const int nrow0 = nbp * 64 + lr;           // n-row for frag j: +j*16
    const float2* sazp = saz2 + (size_t)(kt0 >> 1) * N_DIM + nrow0;

    floatx4 acc[4][4];
    floatx4 zero4 = {0.f, 0.f, 0.f, 0.f};
#pragma unroll
    for (int i = 0; i < 4; ++i)
#pragma unroll
        for (int j = 0; j < 4; ++j)
            acc[i][j] = zero4;

    // prologue: W dwords + A s0-half + raw scales for first group
    unsigned int qw[8], qwn[8];
#pragma unroll
    for (int f = 0; f < 8; ++f)
        qw[f] = wbase[(f >> 2) * 512 + (f & 3) * 16];

    half8 av0[4], av1[4], av0n[4];
#pragma unroll
    for (int i = 0; i < 4; ++i)
        av0[i] = xat[i * 128];

    float2 sf[4];
#pragma unroll
    for (int t = 0; t < 4; ++t)
        sf[t] = sazp[t * 16];

    __half2 s2[4], z2[4];

    for (int kt = kt0; kt < kt1; ++kt) {
        const bool more = (kt + 1 < kt1);

        // convert prefetched scales (VALU-only; sf loaded >=1 kt ago)
        if ((kt & 1) == 0) {
#pragma unroll
            for (int t = 0; t < 4; ++t) {
                s2[t] = __float2half2_rn(sf[t].x);
                z2[t] = __float2half2_rn(fmaf(-8.f, sf[t].x, sf[t].y));
            }
        } else if (more) {
            // issue raw-scale loads for the next group during the odd kt
            sazp += N_DIM;
#pragma unroll
            for (int t = 0; t < 4; ++t)
                sf[t] = sazp[t * 16];
        }

        // issue next-kt W prefetch
        if (more) {
            wbase += 1024;
#pragma unroll
            for (int f = 0; f < 8; ++f)
                qwn[f] = wbase[(f >> 2) * 512 + (f & 3) * 16];
        }

        // issue this-kt s1-half A loads (consumed after the s0 MFMA block)
#pragma unroll
        for (int i = 0; i < 4; ++i)
            av1[i] = xat[i * 128 + 64];

        // s01 = 0: dequant + 16 MFMA on av0 (prefetched during prev iter)
#pragma unroll
        for (int j = 0; j < 4; ++j) {
            half8 bv = dequant8(qw[j], s2[j], z2[j]);
#pragma unroll
            for (int i = 0; i < 4; ++i)
                acc[i][j] = __builtin_amdgcn_mfma_f32_16x16x32_f16(
                    av0[i], bv, acc[i][j], 0, 0, 0);
        }

        // issue next-kt s0-half A loads (consumed next iteration)
        if (more) {
#pragma unroll
            for (int i = 0; i < 4; ++i)
                av0n[i] = xat[1024 + i * 128];
        }

        // s01 = 1: dequant + 16 MFMA on av1 (covered by the s0 block)
#pragma unroll
        for (int j = 0; j < 4; ++j) {
            half8 bv = dequant8(qw[4 + j], s2[j], z2[j]);
#pragma unroll
            for (int i = 0; i < 4; ++i)
                acc[i][j] = __builtin_amdgcn_mfma_f32_16x16x32_f16(
                    av1[i], bv, acc[i][j], 0, 0, 0);
        }

        xat += 1024;
#pragma unroll
        for (int i = 0; i < 4; ++i) av0[i] = av0n[i];
#pragma unroll
        for (int f = 0; f < 8; ++f) qw[f] = qwn[f];
    }

    // ---------------------------------------------------------------------
    // Epilogue: C/D layout col = lane&15 (n), row = q4*4 + reg (m).
    // Cross-wave reduction through padded LDS; nontemporal stores,
    // no atomics (exact R4 artifact).
    // ---------------------------------------------------------------------
    __shared__ float red[2][32 * 65];
    float* don = red[wid];
    const int id0 = wid ? 0 : 2;               // donated i-range
#pragma unroll
    for (int ii = 0; ii < 2; ++ii) {
        const int i = id0 + ii;
#pragma unroll
        for (int j = 0; j < 4; ++j)
#pragma unroll
            for (int rr = 0; rr < 4; ++rr) {
                const int rl = (i * 16 + q4 * 4 + rr) & 31;
                don[rl * 65 + j * 16 + lr] = acc[i][j][rr];
            }
    }
    __syncthreads();
    const float* oth = red[wid ^ 1];
    const int ik0 = wid ? 2 : 0;               // kept i-range
    const int n0 = nbp * 64 + lr;
#pragma unroll
    for (int ii = 0; ii < 2; ++ii) {
        const int i = ik0 + ii;
#pragma unroll
        for (int j = 0; j < 4; ++j) {
            float* o = out + (size_t)(mbp * 64 + i * 16 + q4 * 4) * N_DIM + (n0 + j * 16);
#pragma unroll
            for (int rr = 0; rr < 4; ++rr) {
                const int rl = (i * 16 + q4 * 4 + rr) & 31;
                __builtin_nontemporal_store(acc[i][j][rr] + oth[rl * 65 + j * 16 + lr],
                                            o + (size_t)rr * N_DIM);
            }
        }
    }
}

extern "C" void kernel_launch(void* const* d_in, const int* in_sizes, int n_in,
                              void* d_out, int out_size, void* d_ws, size_t ws_size,
                              hipStream_t stream) {
    const float* x   = (const float*)d_in[0];
    const int*   wq  = (const int*)d_in[1];
    const float* saz = (const float*)d_in[2];

    // ws layout: [wpk: 22,544,384 B packed weights][xb: 4 MB f16 x]
    unsigned int* wpk = (unsigned int*)d_ws;
    unsigned int* xb  = (unsigned int*)((char*)d_ws + 22544384);

    // No output memset: gemm writes every element exactly once (no atomics).
    prep_kernel<<<dim3(12032), dim3(256), 0, stream>>>(x, xb, wq, wpk);
    gemm_kernel<<<dim3(NBLK), dim3(128), 0, stream>>>(xb, wpk, saz, (float*)d_out);
}